// Round 1
// baseline (12224.171 us; speedup 1.0000x reference)
//
#include <hip/hip_runtime.h>

static constexpr int NUSERS = 100000;
static constexpr int NITEMS = 50000;
static constexpr int NNODES = NUSERS + NITEMS;   // 150000
static constexpr int D      = 64;
static constexpr int NNZE   = 4800000;           // edges (COO entries)
static constexpr int NVEC4  = NNODES * D / 4;    // 2,400,000 float4
static constexpr int NU4    = NUSERS * D / 4;    // 1,600,000 float4

// Stage ego = concat(user_emb, item_emb) into x and into out (acc starts at ego).
__global__ void lg_init(const float4* __restrict__ ue, const float4* __restrict__ ie,
                        float4* __restrict__ x, float4* __restrict__ out) {
    int stride = gridDim.x * blockDim.x;
    for (int i = blockIdx.x * blockDim.x + threadIdx.x; i < NVEC4; i += stride) {
        float4 v = (i < NU4) ? ue[i] : ie[i - NU4];
        x[i] = v;
        out[i] = v;
    }
}

// COO SpMM scatter-add: 16 lanes per edge, each lane handles one float4 (4 cols).
__global__ void lg_spmm(const float* __restrict__ vals, const int* __restrict__ rows,
                        const int* __restrict__ cols, const float4* __restrict__ x,
                        float* __restrict__ y) {
    const long long total = (long long)NNZE * 16;
    long long stride = (long long)gridDim.x * blockDim.x;
    for (long long g = (long long)blockIdx.x * blockDim.x + threadIdx.x; g < total; g += stride) {
        int e   = (int)(g >> 4);
        int sub = (int)(g & 15);
        float v = vals[e];
        int c = cols[e];
        int r = rows[e];
        float4 xv = x[(size_t)c * 16 + sub];
        float* dst = y + (size_t)r * 64 + sub * 4;
        unsafeAtomicAdd(dst + 0, v * xv.x);
        unsafeAtomicAdd(dst + 1, v * xv.y);
        unsafeAtomicAdd(dst + 2, v * xv.z);
        unsafeAtomicAdd(dst + 3, v * xv.w);
    }
}

// out += y
__global__ void lg_acc(float4* __restrict__ out, const float4* __restrict__ y) {
    int stride = gridDim.x * blockDim.x;
    for (int i = blockIdx.x * blockDim.x + threadIdx.x; i < NVEC4; i += stride) {
        float4 o = out[i];
        float4 a = y[i];
        o.x += a.x; o.y += a.y; o.z += a.z; o.w += a.w;
        out[i] = o;
    }
}

// out = (out + y) * 0.25
__global__ void lg_acc_final(float4* __restrict__ out, const float4* __restrict__ y) {
    int stride = gridDim.x * blockDim.x;
    for (int i = blockIdx.x * blockDim.x + threadIdx.x; i < NVEC4; i += stride) {
        float4 o = out[i];
        float4 a = y[i];
        o.x = (o.x + a.x) * 0.25f;
        o.y = (o.y + a.y) * 0.25f;
        o.z = (o.z + a.z) * 0.25f;
        o.w = (o.w + a.w) * 0.25f;
        out[i] = o;
    }
}

extern "C" void kernel_launch(void* const* d_in, const int* in_sizes, int n_in,
                              void* d_out, int out_size, void* d_ws, size_t ws_size,
                              hipStream_t stream) {
    const float* ue   = (const float*)d_in[0];  // [100000,64]
    const float* ie   = (const float*)d_in[1];  // [50000,64]
    const float* vals = (const float*)d_in[2];  // [4.8M]
    const int*   rows = (const int*)d_in[3];    // [4.8M]
    const int*   cols = (const int*)d_in[4];    // [4.8M]
    float* out = (float*)d_out;                 // [150000,64]

    float* xa = (float*)d_ws;                       // [N*64]
    float* xb = xa + (size_t)NNODES * D;            // [N*64]
    const size_t xbytes = (size_t)NNODES * D * sizeof(float);

    const int BLK = 256;
    const int gridElem = 2048;   // grid-stride over 2.4M float4
    const int gridSpmm = 4096;   // grid-stride over 76.8M edge-lanes

    lg_init<<<gridElem, BLK, 0, stream>>>((const float4*)ue, (const float4*)ie,
                                          (float4*)xa, (float4*)out);

    float* src = xa;
    float* dst = xb;
    for (int l = 0; l < 3; ++l) {
        hipMemsetAsync(dst, 0, xbytes, stream);
        lg_spmm<<<gridSpmm, BLK, 0, stream>>>(vals, rows, cols, (const float4*)src, dst);
        if (l < 2) {
            lg_acc<<<gridElem, BLK, 0, stream>>>((float4*)out, (const float4*)dst);
        } else {
            lg_acc_final<<<gridElem, BLK, 0, stream>>>((float4*)out, (const float4*)dst);
        }
        float* t = src; src = dst; dst = t;
    }
}

// Round 2
// 1519.803 us; speedup vs baseline: 8.0433x; 8.0433x over previous
//
#include <hip/hip_runtime.h>

static constexpr int NUSERS = 100000;
static constexpr int NITEMS = 50000;
static constexpr int NNODES = NUSERS + NITEMS;   // 150000
static constexpr int D      = 64;
static constexpr int NNZE   = 4800000;           // COO entries
static constexpr int NVEC4  = NNODES * D / 4;    // 2,400,000 float4
static constexpr int NU4    = NUSERS * D / 4;    // 1,600,000 float4

static constexpr int SCAN_BLK = 1024;
static constexpr int SCAN_NB  = (NNODES + SCAN_BLK - 1) / SCAN_BLK;  // 147

// ---------- stage ego = concat(user_emb, item_emb) into xa ----------
__global__ void lg_init(const float4* __restrict__ ue, const float4* __restrict__ ie,
                        float4* __restrict__ x) {
    int stride = gridDim.x * blockDim.x;
    for (int i = blockIdx.x * blockDim.x + threadIdx.x; i < NVEC4; i += stride)
        x[i] = (i < NU4) ? ue[i] : ie[i - NU4];
}

// ---------- CSR build: histogram ----------
__global__ void lg_hist(const int* __restrict__ rows, int* __restrict__ cnt) {
    int stride = gridDim.x * blockDim.x;
    for (int e = blockIdx.x * blockDim.x + threadIdx.x; e < NNZE; e += stride)
        atomicAdd(&cnt[rows[e]], 1);
}

// ---------- CSR build: hierarchical exclusive scan (3 kernels) ----------
__global__ void lg_scan1(const int* __restrict__ cnt, int* __restrict__ rowptr,
                         int* __restrict__ bsum) {
    __shared__ int s[SCAN_BLK];
    int t = threadIdx.x;
    int i = blockIdx.x * SCAN_BLK + t;
    int v = (i < NNODES) ? cnt[i] : 0;
    s[t] = v;
    __syncthreads();
    for (int off = 1; off < SCAN_BLK; off <<= 1) {
        int tmp = (t >= off) ? s[t - off] : 0;
        __syncthreads();
        s[t] += tmp;
        __syncthreads();
    }
    if (i < NNODES) rowptr[i + 1] = s[t];           // inclusive partial
    if (t == SCAN_BLK - 1) bsum[blockIdx.x] = s[t]; // block total
}

__global__ void lg_scan2(int* __restrict__ bsum) {
    __shared__ int s[256];
    int t = threadIdx.x;
    int v = (t < SCAN_NB) ? bsum[t] : 0;
    s[t] = v;
    __syncthreads();
    for (int off = 1; off < 256; off <<= 1) {
        int tmp = (t >= off) ? s[t - off] : 0;
        __syncthreads();
        s[t] += tmp;
        __syncthreads();
    }
    if (t < SCAN_NB) bsum[t] = s[t] - v;            // exclusive block prefix
}

__global__ void lg_scan3(int* __restrict__ rowptr, const int* __restrict__ bsum) {
    int i = blockIdx.x * SCAN_BLK + threadIdx.x;
    if (i < NNODES) rowptr[i + 1] += bsum[blockIdx.x];
    if (i == 0) rowptr[0] = 0;
}

// ---------- CSR build: scatter edge ids into row-grouped perm ----------
__global__ void lg_scatter(const int* __restrict__ rows, const int* __restrict__ rowptr,
                           int* __restrict__ cur, int* __restrict__ perm) {
    int stride = gridDim.x * blockDim.x;
    for (int e = blockIdx.x * blockDim.x + threadIdx.x; e < NNZE; e += stride) {
        int r = rows[e];
        int pos = rowptr[r] + atomicAdd(&cur[r], 1);
        perm[pos] = e;
    }
}

// ---------- pull-style SpMM, 16 lanes per row, fused accumulate ----------
// MODE 0: y = A*x;  out = x_row + y   (x = ego)
// MODE 1: y = A*x;  out += y
// MODE 2: out = (out + A*x) * 0.25    (no y write)
template<int MODE>
__global__ void __launch_bounds__(256)
lg_spmm(const int* __restrict__ rowptr, const int* __restrict__ perm,
        const int* __restrict__ cols, const float* __restrict__ vals,
        const float4* __restrict__ x, float4* __restrict__ y, float4* __restrict__ out) {
    int lane16 = threadIdx.x & 15;
    int r = (blockIdx.x * blockDim.x + threadIdx.x) >> 4;   // one 16-lane group per row
    if (r >= NNODES) return;
    int p0 = rowptr[r], p1 = rowptr[r + 1];
    float4 acc = {0.f, 0.f, 0.f, 0.f};
    int p = p0;
    // unroll 4 for memory-level parallelism through the perm->cols/vals->x chain
    for (; p + 4 <= p1; p += 4) {
        int e0 = perm[p], e1 = perm[p + 1], e2 = perm[p + 2], e3 = perm[p + 3];
        int c0 = cols[e0], c1 = cols[e1], c2 = cols[e2], c3 = cols[e3];
        float v0 = vals[e0], v1 = vals[e1], v2 = vals[e2], v3 = vals[e3];
        float4 x0 = x[c0 * 16 + lane16];
        float4 x1 = x[c1 * 16 + lane16];
        float4 x2 = x[c2 * 16 + lane16];
        float4 x3 = x[c3 * 16 + lane16];
        acc.x += v0 * x0.x + v1 * x1.x + v2 * x2.x + v3 * x3.x;
        acc.y += v0 * x0.y + v1 * x1.y + v2 * x2.y + v3 * x3.y;
        acc.z += v0 * x0.z + v1 * x1.z + v2 * x2.z + v3 * x3.z;
        acc.w += v0 * x0.w + v1 * x1.w + v2 * x2.w + v3 * x3.w;
    }
    for (; p < p1; ++p) {
        int e0 = perm[p];
        int c0 = cols[e0];
        float v0 = vals[e0];
        float4 x0 = x[c0 * 16 + lane16];
        acc.x += v0 * x0.x; acc.y += v0 * x0.y;
        acc.z += v0 * x0.z; acc.w += v0 * x0.w;
    }
    int idx = r * 16 + lane16;
    if (MODE == 0) {
        float4 ego = x[idx];
        y[idx] = acc;
        float4 o;
        o.x = ego.x + acc.x; o.y = ego.y + acc.y;
        o.z = ego.z + acc.z; o.w = ego.w + acc.w;
        out[idx] = o;
    } else if (MODE == 1) {
        y[idx] = acc;
        float4 o = out[idx];
        o.x += acc.x; o.y += acc.y; o.z += acc.z; o.w += acc.w;
        out[idx] = o;
    } else {
        float4 o = out[idx];
        o.x = (o.x + acc.x) * 0.25f;
        o.y = (o.y + acc.y) * 0.25f;
        o.z = (o.z + acc.z) * 0.25f;
        o.w = (o.w + acc.w) * 0.25f;
        out[idx] = o;
    }
}

extern "C" void kernel_launch(void* const* d_in, const int* in_sizes, int n_in,
                              void* d_out, int out_size, void* d_ws, size_t ws_size,
                              hipStream_t stream) {
    const float* ue   = (const float*)d_in[0];
    const float* ie   = (const float*)d_in[1];
    const float* vals = (const float*)d_in[2];
    const int*   rows = (const int*)d_in[3];
    const int*   cols = (const int*)d_in[4];
    float* out = (float*)d_out;

    // workspace layout (~97.2 MB)
    float* xa     = (float*)d_ws;                    // 38.4 MB
    float* xb     = xa + (size_t)NNODES * D;         // 38.4 MB
    int*   perm   = (int*)(xb + (size_t)NNODES * D); // 19.2 MB
    int*   rowptr = perm + NNZE;                     // 150001 ints
    int*   cnt    = rowptr + (NNODES + 1);           // 150000 ints
    int*   bsum   = cnt + NNODES;                    // up to 1024 ints

    const int BLK = 256;

    // ego staging + CSR build (reused by all 3 layers)
    lg_init<<<2048, BLK, 0, stream>>>((const float4*)ue, (const float4*)ie, (float4*)xa);
    hipMemsetAsync(cnt, 0, NNODES * sizeof(int), stream);
    lg_hist<<<4096, BLK, 0, stream>>>(rows, cnt);
    lg_scan1<<<SCAN_NB, SCAN_BLK, 0, stream>>>(cnt, rowptr, bsum);
    lg_scan2<<<1, 256, 0, stream>>>(bsum);
    lg_scan3<<<SCAN_NB, SCAN_BLK, 0, stream>>>(rowptr, bsum);
    hipMemsetAsync(cnt, 0, NNODES * sizeof(int), stream);
    lg_scatter<<<4096, BLK, 0, stream>>>(rows, rowptr, cnt, perm);

    // 3 fused SpMM layers (one wave-quarter per row, register accumulation)
    const int spmmBlocks = (NNODES * 16 + BLK - 1) / BLK;  // 9375
    lg_spmm<0><<<spmmBlocks, BLK, 0, stream>>>(rowptr, perm, cols, vals,
                                               (const float4*)xa, (float4*)xb, (float4*)out);
    lg_spmm<1><<<spmmBlocks, BLK, 0, stream>>>(rowptr, perm, cols, vals,
                                               (const float4*)xb, (float4*)xa, (float4*)out);
    lg_spmm<2><<<spmmBlocks, BLK, 0, stream>>>(rowptr, perm, cols, vals,
                                               (const float4*)xa, nullptr, (float4*)out);
}

// Round 3
// 1074.551 us; speedup vs baseline: 11.3761x; 1.4144x over previous
//
#include <hip/hip_runtime.h>

static constexpr int NUSERS = 100000;
static constexpr int NITEMS = 50000;
static constexpr int NNODES = NUSERS + NITEMS;   // 150000
static constexpr int D      = 64;
static constexpr int NNZE   = 4800000;           // COO entries
static constexpr int NVEC4  = NNODES * D / 4;    // 2,400,000 float4
static constexpr int NU4    = NUSERS * D / 4;    // 1,600,000 float4

static constexpr int SCAN_BLK = 1024;
static constexpr int SCAN_NB  = (NNODES + SCAN_BLK - 1) / SCAN_BLK;  // 147

// ---------- stage ego = concat(user_emb, item_emb) into xa ----------
__global__ void lg_init(const float4* __restrict__ ue, const float4* __restrict__ ie,
                        float4* __restrict__ x) {
    int stride = gridDim.x * blockDim.x;
    for (int i = blockIdx.x * blockDim.x + threadIdx.x; i < NVEC4; i += stride)
        x[i] = (i < NU4) ? ue[i] : ie[i - NU4];
}

// ---------- CSR build: histogram (int4 loads, 4 edges/thread/iter) ----------
__global__ void lg_hist(const int4* __restrict__ rows4, int* __restrict__ cnt) {
    int stride = gridDim.x * blockDim.x;
    for (int i = blockIdx.x * blockDim.x + threadIdx.x; i < NNZE / 4; i += stride) {
        int4 r = rows4[i];
        atomicAdd(&cnt[r.x], 1);
        atomicAdd(&cnt[r.y], 1);
        atomicAdd(&cnt[r.z], 1);
        atomicAdd(&cnt[r.w], 1);
    }
}

// ---------- CSR build: hierarchical exclusive scan (3 kernels) ----------
__global__ void lg_scan1(const int* __restrict__ cnt, int* __restrict__ rowptr,
                         int* __restrict__ bsum) {
    __shared__ int s[SCAN_BLK];
    int t = threadIdx.x;
    int i = blockIdx.x * SCAN_BLK + t;
    int v = (i < NNODES) ? cnt[i] : 0;
    s[t] = v;
    __syncthreads();
    for (int off = 1; off < SCAN_BLK; off <<= 1) {
        int tmp = (t >= off) ? s[t - off] : 0;
        __syncthreads();
        s[t] += tmp;
        __syncthreads();
    }
    if (i < NNODES) rowptr[i + 1] = s[t];           // inclusive partial
    if (t == SCAN_BLK - 1) bsum[blockIdx.x] = s[t]; // block total
}

__global__ void lg_scan2(int* __restrict__ bsum) {
    __shared__ int s[256];
    int t = threadIdx.x;
    int v = (t < SCAN_NB) ? bsum[t] : 0;
    s[t] = v;
    __syncthreads();
    for (int off = 1; off < 256; off <<= 1) {
        int tmp = (t >= off) ? s[t - off] : 0;
        __syncthreads();
        s[t] += tmp;
        __syncthreads();
    }
    if (t < SCAN_NB) bsum[t] = s[t] - v;            // exclusive block prefix
}

__global__ void lg_scan3(int* __restrict__ rowptr, const int* __restrict__ bsum) {
    int i = blockIdx.x * SCAN_BLK + threadIdx.x;
    if (i < NNODES) rowptr[i + 1] += bsum[blockIdx.x];
    if (i == 0) rowptr[0] = 0;
}

// ---------- CSR build: scatter (col, val) payload into row-grouped order ----------
// cur[] is pre-seeded with rowptr[] so one atomic gives the final position.
__global__ void lg_scatter_fused(const int* __restrict__ rows, const int* __restrict__ cols,
                                 const float* __restrict__ vals, int* __restrict__ cur,
                                 int2* __restrict__ csr) {
    int stride = gridDim.x * blockDim.x;
    for (int e = blockIdx.x * blockDim.x + threadIdx.x; e < NNZE; e += stride) {
        int r = rows[e];
        int pos = atomicAdd(&cur[r], 1);
        int2 cv;
        cv.x = cols[e];
        cv.y = __float_as_int(vals[e]);
        csr[pos] = cv;
    }
}

// fallback (small-ws): scatter only edge ids
__global__ void lg_scatter_perm(const int* __restrict__ rows, int* __restrict__ cur,
                                int* __restrict__ perm) {
    int stride = gridDim.x * blockDim.x;
    for (int e = blockIdx.x * blockDim.x + threadIdx.x; e < NNZE; e += stride) {
        int r = rows[e];
        int pos = atomicAdd(&cur[r], 1);
        perm[pos] = e;
    }
}

// ---------- pull-style SpMM, 16 lanes per row, fused accumulate ----------
// MODE 0: y = A*x;  out = x_row + y   (x = ego)
// MODE 1: y = A*x;  out += y
// MODE 2: out = (out + A*x) * 0.25    (no y write)
// FUSED=true: sequential int2 csr payload.  FUSED=false: perm->cols/vals gathers.
template<int MODE, bool FUSED>
__global__ void __launch_bounds__(256)
lg_spmm(const int* __restrict__ rowptr, const int2* __restrict__ csr,
        const int* __restrict__ perm, const int* __restrict__ cols,
        const float* __restrict__ vals,
        const float4* __restrict__ x, float4* __restrict__ y, float4* __restrict__ out) {
    int lane16 = threadIdx.x & 15;
    int r = (blockIdx.x * blockDim.x + threadIdx.x) >> 4;   // one 16-lane group per row
    if (r >= NNODES) return;
    int p0 = rowptr[r], p1 = rowptr[r + 1];
    float4 acc = {0.f, 0.f, 0.f, 0.f};
    int p = p0;
    if (FUSED) {
        for (; p + 4 <= p1; p += 4) {
            int2 cv0 = csr[p], cv1 = csr[p + 1], cv2 = csr[p + 2], cv3 = csr[p + 3];
            float4 x0 = x[cv0.x * 16 + lane16];
            float4 x1 = x[cv1.x * 16 + lane16];
            float4 x2 = x[cv2.x * 16 + lane16];
            float4 x3 = x[cv3.x * 16 + lane16];
            float v0 = __int_as_float(cv0.y), v1 = __int_as_float(cv1.y);
            float v2 = __int_as_float(cv2.y), v3 = __int_as_float(cv3.y);
            acc.x += v0 * x0.x + v1 * x1.x + v2 * x2.x + v3 * x3.x;
            acc.y += v0 * x0.y + v1 * x1.y + v2 * x2.y + v3 * x3.y;
            acc.z += v0 * x0.z + v1 * x1.z + v2 * x2.z + v3 * x3.z;
            acc.w += v0 * x0.w + v1 * x1.w + v2 * x2.w + v3 * x3.w;
        }
        for (; p < p1; ++p) {
            int2 cv = csr[p];
            float4 xv = x[cv.x * 16 + lane16];
            float v = __int_as_float(cv.y);
            acc.x += v * xv.x; acc.y += v * xv.y;
            acc.z += v * xv.z; acc.w += v * xv.w;
        }
    } else {
        for (; p + 4 <= p1; p += 4) {
            int e0 = perm[p], e1 = perm[p + 1], e2 = perm[p + 2], e3 = perm[p + 3];
            int c0 = cols[e0], c1 = cols[e1], c2 = cols[e2], c3 = cols[e3];
            float v0 = vals[e0], v1 = vals[e1], v2 = vals[e2], v3 = vals[e3];
            float4 x0 = x[c0 * 16 + lane16];
            float4 x1 = x[c1 * 16 + lane16];
            float4 x2 = x[c2 * 16 + lane16];
            float4 x3 = x[c3 * 16 + lane16];
            acc.x += v0 * x0.x + v1 * x1.x + v2 * x2.x + v3 * x3.x;
            acc.y += v0 * x0.y + v1 * x1.y + v2 * x2.y + v3 * x3.y;
            acc.z += v0 * x0.z + v1 * x1.z + v2 * x2.z + v3 * x3.z;
            acc.w += v0 * x0.w + v1 * x1.w + v2 * x2.w + v3 * x3.w;
        }
        for (; p < p1; ++p) {
            int e0 = perm[p];
            float v = vals[e0];
            float4 xv = x[cols[e0] * 16 + lane16];
            acc.x += v * xv.x; acc.y += v * xv.y;
            acc.z += v * xv.z; acc.w += v * xv.w;
        }
    }
    int idx = r * 16 + lane16;
    if (MODE == 0) {
        float4 ego = x[idx];
        y[idx] = acc;
        float4 o;
        o.x = ego.x + acc.x; o.y = ego.y + acc.y;
        o.z = ego.z + acc.z; o.w = ego.w + acc.w;
        out[idx] = o;
    } else if (MODE == 1) {
        y[idx] = acc;
        float4 o = out[idx];
        o.x += acc.x; o.y += acc.y; o.z += acc.z; o.w += acc.w;
        out[idx] = o;
    } else {
        float4 o = out[idx];
        o.x = (o.x + acc.x) * 0.25f;
        o.y = (o.y + acc.y) * 0.25f;
        o.z = (o.z + acc.z) * 0.25f;
        o.w = (o.w + acc.w) * 0.25f;
        out[idx] = o;
    }
}

extern "C" void kernel_launch(void* const* d_in, const int* in_sizes, int n_in,
                              void* d_out, int out_size, void* d_ws, size_t ws_size,
                              hipStream_t stream) {
    const float* ue   = (const float*)d_in[0];
    const float* ie   = (const float*)d_in[1];
    const float* vals = (const float*)d_in[2];
    const int*   rows = (const int*)d_in[3];
    const int*   cols = (const int*)d_in[4];
    float* out = (float*)d_out;

    const size_t xfloats = (size_t)NNODES * D;           // 9.6M floats = 38.4 MB
    const size_t fusedNeed = 3 * xfloats * 4 + (size_t)(NNODES + 1 + NNODES + 1024) * 4;
    const bool fused = ws_size >= fusedNeed + 4096;

    float* xa = (float*)d_ws;
    float* xb = xa + xfloats;
    const int BLK = 256;
    const int spmmBlocks = (NNODES * 16 + BLK - 1) / BLK;  // 9375

    if (fused) {
        int2* csr    = (int2*)(xb + xfloats);            // 38.4 MB
        int*  rowptr = (int*)(csr + NNZE);
        int*  cur    = rowptr + (NNODES + 1);
        int*  bsum   = cur + NNODES;

        lg_init<<<2048, BLK, 0, stream>>>((const float4*)ue, (const float4*)ie, (float4*)xa);
        hipMemsetAsync(cur, 0, NNODES * sizeof(int), stream);
        lg_hist<<<2048, BLK, 0, stream>>>((const int4*)rows, cur);
        lg_scan1<<<SCAN_NB, SCAN_BLK, 0, stream>>>(cur, rowptr, bsum);
        lg_scan2<<<1, 256, 0, stream>>>(bsum);
        lg_scan3<<<SCAN_NB, SCAN_BLK, 0, stream>>>(rowptr, bsum);
        hipMemcpyAsync(cur, rowptr, NNODES * sizeof(int), hipMemcpyDeviceToDevice, stream);
        lg_scatter_fused<<<4096, BLK, 0, stream>>>(rows, cols, vals, cur, csr);

        lg_spmm<0, true><<<spmmBlocks, BLK, 0, stream>>>(rowptr, csr, nullptr, nullptr, nullptr,
                                                         (const float4*)xa, (float4*)xb, (float4*)out);
        lg_spmm<1, true><<<spmmBlocks, BLK, 0, stream>>>(rowptr, csr, nullptr, nullptr, nullptr,
                                                         (const float4*)xb, (float4*)xa, (float4*)out);
        lg_spmm<2, true><<<spmmBlocks, BLK, 0, stream>>>(rowptr, csr, nullptr, nullptr, nullptr,
                                                         (const float4*)xa, nullptr, (float4*)out);
    } else {
        int* perm   = (int*)(xb + xfloats);              // 19.2 MB
        int* rowptr = perm + NNZE;
        int* cur    = rowptr + (NNODES + 1);
        int* bsum   = cur + NNODES;

        lg_init<<<2048, BLK, 0, stream>>>((const float4*)ue, (const float4*)ie, (float4*)xa);
        hipMemsetAsync(cur, 0, NNODES * sizeof(int), stream);
        lg_hist<<<2048, BLK, 0, stream>>>((const int4*)rows, cur);
        lg_scan1<<<SCAN_NB, SCAN_BLK, 0, stream>>>(cur, rowptr, bsum);
        lg_scan2<<<1, 256, 0, stream>>>(bsum);
        lg_scan3<<<SCAN_NB, SCAN_BLK, 0, stream>>>(rowptr, bsum);
        hipMemcpyAsync(cur, rowptr, NNODES * sizeof(int), hipMemcpyDeviceToDevice, stream);
        lg_scatter_perm<<<4096, BLK, 0, stream>>>(rows, cur, perm);

        lg_spmm<0, false><<<spmmBlocks, BLK, 0, stream>>>(rowptr, nullptr, perm, cols, vals,
                                                          (const float4*)xa, (float4*)xb, (float4*)out);
        lg_spmm<1, false><<<spmmBlocks, BLK, 0, stream>>>(rowptr, nullptr, perm, cols, vals,
                                                          (const float4*)xb, (float4*)xa, (float4*)out);
        lg_spmm<2, false><<<spmmBlocks, BLK, 0, stream>>>(rowptr, nullptr, perm, cols, vals,
                                                          (const float4*)xa, nullptr, (float4*)out);
    }
}

// Round 4
// 594.944 us; speedup vs baseline: 20.5468x; 1.8061x over previous
//
#include <hip/hip_runtime.h>

static constexpr int NUSERS = 100000;
static constexpr int NITEMS = 50000;
static constexpr int NNODES = NUSERS + NITEMS;   // 150000
static constexpr int D      = 64;
static constexpr int NNZE   = 4800000;           // COO entries
static constexpr int NVEC4  = NNODES * D / 4;    // 2.4M 4-col groups
static constexpr int NU4    = NUSERS * D / 4;

static constexpr int SCAN_BLK = 1024;
static constexpr int SCAN_NB  = (NNODES + SCAN_BLK - 1) / SCAN_BLK;  // 147

static constexpr int NB       = 512;                       // buckets
static constexpr int RPB      = (NNODES + NB - 1) / NB;    // 293 rows/bucket
static constexpr int CHUNK    = 8192;                      // edges per part1 block
static constexpr int P1_BLOCKS = (NNZE + CHUNK - 1) / CHUNK; // 586

__device__ __forceinline__ unsigned bf16rne(float f) {
    unsigned u = __float_as_uint(f);
    return (u + 0x7FFFu + ((u >> 16) & 1u)) >> 16;   // round-to-nearest-even bf16
}
__device__ __forceinline__ float bflo(unsigned u) { return __uint_as_float(u << 16); }
__device__ __forceinline__ float bfhi(unsigned u) { return __uint_as_float(u & 0xFFFF0000u); }

// ---------- stage: out = ego (fp32), x = ego (packed bf16) ----------
__global__ void lg_init(const float4* __restrict__ ue, const float4* __restrict__ ie,
                        uint2* __restrict__ x, float4* __restrict__ out) {
    int stride = gridDim.x * blockDim.x;
    for (int i = blockIdx.x * blockDim.x + threadIdx.x; i < NVEC4; i += stride) {
        float4 v = (i < NU4) ? ue[i] : ie[i - NU4];
        out[i] = v;
        x[i] = make_uint2(bf16rne(v.x) | (bf16rne(v.y) << 16),
                          bf16rne(v.z) | (bf16rne(v.w) << 16));
    }
}

// ---------- CSR build: per-row histogram ----------
__global__ void lg_hist(const int4* __restrict__ rows4, int* __restrict__ cnt) {
    int stride = gridDim.x * blockDim.x;
    for (int i = blockIdx.x * blockDim.x + threadIdx.x; i < NNZE / 4; i += stride) {
        int4 r = rows4[i];
        atomicAdd(&cnt[r.x], 1);
        atomicAdd(&cnt[r.y], 1);
        atomicAdd(&cnt[r.z], 1);
        atomicAdd(&cnt[r.w], 1);
    }
}

// ---------- hierarchical exclusive scan ----------
__global__ void lg_scan1(const int* __restrict__ cnt, int* __restrict__ rowptr,
                         int* __restrict__ bsum) {
    __shared__ int s[SCAN_BLK];
    int t = threadIdx.x;
    int i = blockIdx.x * SCAN_BLK + t;
    int v = (i < NNODES) ? cnt[i] : 0;
    s[t] = v;
    __syncthreads();
    for (int off = 1; off < SCAN_BLK; off <<= 1) {
        int tmp = (t >= off) ? s[t - off] : 0;
        __syncthreads();
        s[t] += tmp;
        __syncthreads();
    }
    if (i < NNODES) rowptr[i + 1] = s[t];
    if (t == SCAN_BLK - 1) bsum[blockIdx.x] = s[t];
}

__global__ void lg_scan2(int* __restrict__ bsum) {
    __shared__ int s[256];
    int t = threadIdx.x;
    int v = (t < SCAN_NB) ? bsum[t] : 0;
    s[t] = v;
    __syncthreads();
    for (int off = 1; off < 256; off <<= 1) {
        int tmp = (t >= off) ? s[t - off] : 0;
        __syncthreads();
        s[t] += tmp;
        __syncthreads();
    }
    if (t < SCAN_NB) bsum[t] = s[t] - v;
}

__global__ void lg_scan3(int* __restrict__ rowptr, const int* __restrict__ bsum) {
    int i = blockIdx.x * SCAN_BLK + threadIdx.x;
    if (i < NNODES) rowptr[i + 1] += bsum[blockIdx.x];
    if (i == 0) rowptr[0] = 0;
}

// ---------- seed per-bucket global cursors at bucket segment bases ----------
__global__ void lg_seed(const int* __restrict__ rowptr, int* __restrict__ gcur) {
    int b = blockIdx.x * blockDim.x + threadIdx.x;
    if (b < NB) gcur[b] = rowptr[b * RPB];
}

// ---------- phase 1: LDS-aggregated 512-way bucket partition ----------
// payload: .x = col | (rowLow << 18)  (col < 2^18, rowLow < 293 < 2^9), .y = val bits
__global__ void __launch_bounds__(256)
lg_part1(const int* __restrict__ rows, const int* __restrict__ cols,
         const float* __restrict__ vals, int* __restrict__ gcur,
         int2* __restrict__ stage) {
    __shared__ int cnt[NB];
    __shared__ int base[NB];
    int tid = threadIdx.x;
    int c0 = blockIdx.x * CHUNK;
    int c1 = min(c0 + CHUNK, NNZE);
    for (int b = tid; b < NB; b += 256) cnt[b] = 0;
    __syncthreads();
    for (int e = c0 + tid; e < c1; e += 256)
        atomicAdd(&cnt[rows[e] / RPB], 1);
    __syncthreads();
    for (int b = tid; b < NB; b += 256) {
        int n = cnt[b];
        base[b] = n ? atomicAdd(&gcur[b], n) : 0;   // reserve contiguous chunk
        cnt[b] = 0;                                  // reuse as local cursor
    }
    __syncthreads();
    for (int e = c0 + tid; e < c1; e += 256) {
        int r = rows[e];
        int b = r / RPB;
        int rl = r - b * RPB;
        int k = atomicAdd(&cnt[b], 1);
        stage[base[b] + k] = make_int2(cols[e] | (rl << 18), __float_as_int(vals[e]));
    }
}

// ---------- phase 2: within-bucket exact CSR placement (L2-local writes) ----------
__global__ void __launch_bounds__(256)
lg_part2(const int* __restrict__ rowptr, const int2* __restrict__ stage,
         int2* __restrict__ csr) {
    __shared__ int lcur[RPB];
    int b = blockIdx.x;
    int r0 = b * RPB;
    int r1 = min(r0 + RPB, NNODES);
    int nrows = r1 - r0;
    for (int i = threadIdx.x; i < nrows; i += 256) lcur[i] = rowptr[r0 + i];
    __syncthreads();
    int s0 = rowptr[r0], s1 = rowptr[r1];
    for (int p = s0 + threadIdx.x; p < s1; p += 256) {
        int2 cv = stage[p];
        int rl = (cv.x >> 18) & 511;
        int pos = atomicAdd(&lcur[rl], 1);
        csr[pos] = make_int2(cv.x & 0x3FFFF, cv.y);
    }
}

// ---------- pull SpMM: 16 lanes/row, bf16 gathers, fp32 acc, fused out-update ----------
// MODE 0: y = bf16(A*x); out += A*x      MODE 1: out = (out + A*x) * 0.25
template<int MODE>
__global__ void __launch_bounds__(256)
lg_spmm(const int* __restrict__ rowptr, const int2* __restrict__ csr,
        const uint2* __restrict__ x, uint2* __restrict__ y, float4* __restrict__ out) {
    int lane16 = threadIdx.x & 15;
    int r = (blockIdx.x * blockDim.x + threadIdx.x) >> 4;
    if (r >= NNODES) return;
    int p0 = rowptr[r], p1 = rowptr[r + 1];
    float4 acc = {0.f, 0.f, 0.f, 0.f};
    int p = p0;
    for (; p + 4 <= p1; p += 4) {
        int2 cv0 = csr[p], cv1 = csr[p + 1], cv2 = csr[p + 2], cv3 = csr[p + 3];
        uint2 x0 = x[cv0.x * 16 + lane16];
        uint2 x1 = x[cv1.x * 16 + lane16];
        uint2 x2 = x[cv2.x * 16 + lane16];
        uint2 x3 = x[cv3.x * 16 + lane16];
        float v0 = __int_as_float(cv0.y), v1 = __int_as_float(cv1.y);
        float v2 = __int_as_float(cv2.y), v3 = __int_as_float(cv3.y);
        acc.x += v0 * bflo(x0.x) + v1 * bflo(x1.x) + v2 * bflo(x2.x) + v3 * bflo(x3.x);
        acc.y += v0 * bfhi(x0.x) + v1 * bfhi(x1.x) + v2 * bfhi(x2.x) + v3 * bfhi(x3.x);
        acc.z += v0 * bflo(x0.y) + v1 * bflo(x1.y) + v2 * bflo(x2.y) + v3 * bflo(x3.y);
        acc.w += v0 * bfhi(x0.y) + v1 * bfhi(x1.y) + v2 * bfhi(x2.y) + v3 * bfhi(x3.y);
    }
    for (; p < p1; ++p) {
        int2 cv = csr[p];
        uint2 xv = x[cv.x * 16 + lane16];
        float v = __int_as_float(cv.y);
        acc.x += v * bflo(xv.x); acc.y += v * bfhi(xv.x);
        acc.z += v * bflo(xv.y); acc.w += v * bfhi(xv.y);
    }
    int idx = r * 16 + lane16;
    if (MODE == 0) {
        y[idx] = make_uint2(bf16rne(acc.x) | (bf16rne(acc.y) << 16),
                            bf16rne(acc.z) | (bf16rne(acc.w) << 16));
        float4 o = out[idx];
        o.x += acc.x; o.y += acc.y; o.z += acc.z; o.w += acc.w;
        out[idx] = o;
    } else {
        float4 o = out[idx];
        o.x = (o.x + acc.x) * 0.25f;
        o.y = (o.y + acc.y) * 0.25f;
        o.z = (o.z + acc.z) * 0.25f;
        o.w = (o.w + acc.w) * 0.25f;
        out[idx] = o;
    }
}

extern "C" void kernel_launch(void* const* d_in, const int* in_sizes, int n_in,
                              void* d_out, int out_size, void* d_ws, size_t ws_size,
                              hipStream_t stream) {
    const float* ue   = (const float*)d_in[0];
    const float* ie   = (const float*)d_in[1];
    const float* vals = (const float*)d_in[2];
    const int*   rows = (const int*)d_in[3];
    const int*   cols = (const int*)d_in[4];
    float* out = (float*)d_out;

    // workspace (~115.8 MB; round-3 fused path proved ws >= 116.1 MB)
    uint2* xa    = (uint2*)d_ws;                 // 19.2 MB (bf16 x, ping)
    uint2* xb    = xa + NVEC4;                   // 19.2 MB (bf16 x, pong)
    int2*  csr   = (int2*)(xb + NVEC4);          // 38.4 MB
    int2*  stage = csr + NNZE;                   // 38.4 MB
    int*   cnt   = (int*)stage;                  // alias: hist uses stage's first 600 KB
    int*   rowptr = (int*)(stage + NNZE);        // 150001 ints
    int*   bsum   = rowptr + (NNODES + 1);       // 512 reserved (147 used)
    int*   gcur   = bsum + 512;                  // 512 ints

    const int BLK = 256;
    const int spmmBlocks = NNODES * 16 / BLK;    // 9375

    lg_init<<<2048, BLK, 0, stream>>>((const float4*)ue, (const float4*)ie, xa, (float4*)out);
    hipMemsetAsync(cnt, 0, NNODES * sizeof(int), stream);
    lg_hist<<<2048, BLK, 0, stream>>>((const int4*)rows, cnt);
    lg_scan1<<<SCAN_NB, SCAN_BLK, 0, stream>>>(cnt, rowptr, bsum);
    lg_scan2<<<1, 256, 0, stream>>>(bsum);
    lg_scan3<<<SCAN_NB, SCAN_BLK, 0, stream>>>(rowptr, bsum);
    lg_seed<<<(NB + BLK - 1) / BLK, BLK, 0, stream>>>(rowptr, gcur);
    lg_part1<<<P1_BLOCKS, BLK, 0, stream>>>(rows, cols, vals, gcur, stage);
    lg_part2<<<NB, BLK, 0, stream>>>(rowptr, stage, csr);

    lg_spmm<0><<<spmmBlocks, BLK, 0, stream>>>(rowptr, csr, xa, xb, (float4*)out);
    lg_spmm<0><<<spmmBlocks, BLK, 0, stream>>>(rowptr, csr, xb, xa, (float4*)out);
    lg_spmm<1><<<spmmBlocks, BLK, 0, stream>>>(rowptr, csr, xa, nullptr, (float4*)out);
}

// Round 5
// 391.027 us; speedup vs baseline: 31.2617x; 1.5215x over previous
//
#include <hip/hip_runtime.h>

static constexpr int NUSERS = 100000;
static constexpr int NITEMS = 50000;
static constexpr int NNODES = NUSERS + NITEMS;   // 150000
static constexpr int D      = 64;
static constexpr int NNZE   = 4800000;           // COO entries
static constexpr int NVEC4  = NNODES * D / 4;    // 2.4M 4-col groups
static constexpr int NU4    = NUSERS * D / 4;

static constexpr int NB       = 512;                       // buckets
static constexpr int RPB      = (NNODES + NB - 1) / NB;    // 293 rows/bucket
static constexpr int CHUNK    = 8192;                      // edges per part1 block
static constexpr int P1_BLOCKS = (NNZE + CHUNK - 1) / CHUNK; // 586

__device__ __forceinline__ unsigned bf16rne(float f) {
    unsigned u = __float_as_uint(f);
    return (u + 0x7FFFu + ((u >> 16) & 1u)) >> 16;   // round-to-nearest-even bf16
}
__device__ __forceinline__ float bflo(unsigned u) { return __uint_as_float(u << 16); }
__device__ __forceinline__ float bfhi(unsigned u) { return __uint_as_float(u & 0xFFFF0000u); }

// ---------- stage: out = ego (fp32), x = ego (packed bf16) ----------
__global__ void lg_init(const float4* __restrict__ ue, const float4* __restrict__ ie,
                        uint2* __restrict__ x, float4* __restrict__ out) {
    int stride = gridDim.x * blockDim.x;
    for (int i = blockIdx.x * blockDim.x + threadIdx.x; i < NVEC4; i += stride) {
        float4 v = (i < NU4) ? ue[i] : ie[i - NU4];
        out[i] = v;
        x[i] = make_uint2(bf16rne(v.x) | (bf16rne(v.y) << 16),
                          bf16rne(v.z) | (bf16rne(v.w) << 16));
    }
}

// ---------- bucket-level histogram: LDS-privatized, 512 global atomics/block ----------
__global__ void __launch_bounds__(256)
lg_bcnt(const int* __restrict__ rows, int* __restrict__ bucketCnt) {
    __shared__ int cnt[NB];
    int tid = threadIdx.x;
    for (int b = tid; b < NB; b += 256) cnt[b] = 0;
    __syncthreads();
    int c0 = blockIdx.x * CHUNK;
    int c1 = min(c0 + CHUNK, NNZE);
    for (int e = c0 + tid; e < c1; e += 256)
        atomicAdd(&cnt[rows[e] / RPB], 1);
    __syncthreads();
    for (int b = tid; b < NB; b += 256)
        if (cnt[b]) atomicAdd(&bucketCnt[b], cnt[b]);
}

// ---------- scan 512 bucket counts -> bbase[513]; seed gcur ----------
__global__ void __launch_bounds__(512)
lg_bscan(const int* __restrict__ bucketCnt, int* __restrict__ bbase,
         int* __restrict__ gcur) {
    __shared__ int s[NB];
    int t = threadIdx.x;
    int v = bucketCnt[t];
    s[t] = v;
    __syncthreads();
    for (int off = 1; off < NB; off <<= 1) {
        int tmp = (t >= off) ? s[t - off] : 0;
        __syncthreads();
        s[t] += tmp;
        __syncthreads();
    }
    int ex = s[t] - v;          // exclusive prefix
    bbase[t] = ex;
    gcur[t] = ex;
    if (t == NB - 1) bbase[NB] = s[t];
}

// ---------- phase 1: LDS-aggregated 512-way bucket partition ----------
// payload: .x = col | (rowLow << 18)  (col < 2^18, rowLow < 293 < 2^9), .y = val bits
__global__ void __launch_bounds__(256)
lg_part1(const int* __restrict__ rows, const int* __restrict__ cols,
         const float* __restrict__ vals, int* __restrict__ gcur,
         int2* __restrict__ stage) {
    __shared__ int cnt[NB];
    __shared__ int base[NB];
    int tid = threadIdx.x;
    int c0 = blockIdx.x * CHUNK;
    int c1 = min(c0 + CHUNK, NNZE);
    for (int b = tid; b < NB; b += 256) cnt[b] = 0;
    __syncthreads();
    for (int e = c0 + tid; e < c1; e += 256)
        atomicAdd(&cnt[rows[e] / RPB], 1);
    __syncthreads();
    for (int b = tid; b < NB; b += 256) {
        int n = cnt[b];
        base[b] = n ? atomicAdd(&gcur[b], n) : 0;   // reserve contiguous chunk
        cnt[b] = 0;                                  // reuse as local cursor
    }
    __syncthreads();
    for (int e = c0 + tid; e < c1; e += 256) {
        int r = rows[e];
        int b = r / RPB;
        int rl = r - b * RPB;
        int k = atomicAdd(&cnt[b], 1);
        stage[base[b] + k] = make_int2(cols[e] | (rl << 18), __float_as_int(vals[e]));
    }
}

// ---------- phase 2: per-bucket rowptr build + exact CSR placement ----------
__global__ void __launch_bounds__(512)
lg_part2(const int* __restrict__ bbase, const int2* __restrict__ stage,
         int2* __restrict__ csr, int* __restrict__ rowptr) {
    __shared__ int s[NB];      // padded hist/scan space (RPB=293 <= 512)
    __shared__ int lcur[RPB];
    int b = blockIdx.x;
    int t = threadIdx.x;
    int r0 = b * RPB;
    int nrows = min(RPB, NNODES - r0);
    int s0 = bbase[b], s1 = bbase[b + 1];

    s[t] = 0;
    __syncthreads();
    for (int p = s0 + t; p < s1; p += 512)
        atomicAdd(&s[(stage[p].x >> 18) & 511], 1);
    __syncthreads();
    int v = s[t];
    // inclusive Hillis-Steele scan over 512 slots
    for (int off = 1; off < NB; off <<= 1) {
        int tmp = (t >= off) ? s[t - off] : 0;
        __syncthreads();
        s[t] += tmp;
        __syncthreads();
    }
    int pos0 = s0 + s[t] - v;  // exclusive prefix + bucket base
    if (t < nrows) {
        rowptr[r0 + t] = pos0;
        lcur[t] = pos0;
    }
    if (b == gridDim.x - 1 && t == 0) rowptr[NNODES] = NNZE;
    __syncthreads();
    for (int p = s0 + t; p < s1; p += 512) {
        int2 cv = stage[p];
        int rl = (cv.x >> 18) & 511;
        int pos = atomicAdd(&lcur[rl], 1);
        csr[pos] = make_int2(cv.x & 0x3FFFF, cv.y);
    }
}

// ---------- pull SpMM: 16 lanes/row, bf16 gathers, fp32 acc, fused out-update ----------
// MODE 0: y = bf16(A*x); out += A*x      MODE 1: out = (out + A*x) * 0.25
template<int MODE>
__global__ void __launch_bounds__(256)
lg_spmm(const int* __restrict__ rowptr, const int2* __restrict__ csr,
        const uint2* __restrict__ x, uint2* __restrict__ y, float4* __restrict__ out) {
    int lane16 = threadIdx.x & 15;
    int r = (blockIdx.x * blockDim.x + threadIdx.x) >> 4;
    if (r >= NNODES) return;
    int p0 = rowptr[r], p1 = rowptr[r + 1];
    float4 acc = {0.f, 0.f, 0.f, 0.f};
    int p = p0;
    for (; p + 4 <= p1; p += 4) {
        int2 cv0 = csr[p], cv1 = csr[p + 1], cv2 = csr[p + 2], cv3 = csr[p + 3];
        uint2 x0 = x[cv0.x * 16 + lane16];
        uint2 x1 = x[cv1.x * 16 + lane16];
        uint2 x2 = x[cv2.x * 16 + lane16];
        uint2 x3 = x[cv3.x * 16 + lane16];
        float v0 = __int_as_float(cv0.y), v1 = __int_as_float(cv1.y);
        float v2 = __int_as_float(cv2.y), v3 = __int_as_float(cv3.y);
        acc.x += v0 * bflo(x0.x) + v1 * bflo(x1.x) + v2 * bflo(x2.x) + v3 * bflo(x3.x);
        acc.y += v0 * bfhi(x0.x) + v1 * bfhi(x1.x) + v2 * bfhi(x2.x) + v3 * bfhi(x3.x);
        acc.z += v0 * bflo(x0.y) + v1 * bflo(x1.y) + v2 * bflo(x2.y) + v3 * bflo(x3.y);
        acc.w += v0 * bfhi(x0.y) + v1 * bfhi(x1.y) + v2 * bfhi(x2.y) + v3 * bfhi(x3.y);
    }
    for (; p < p1; ++p) {
        int2 cv = csr[p];
        uint2 xv = x[cv.x * 16 + lane16];
        float v = __int_as_float(cv.y);
        acc.x += v * bflo(xv.x); acc.y += v * bfhi(xv.x);
        acc.z += v * bflo(xv.y); acc.w += v * bfhi(xv.y);
    }
    int idx = r * 16 + lane16;
    if (MODE == 0) {
        y[idx] = make_uint2(bf16rne(acc.x) | (bf16rne(acc.y) << 16),
                            bf16rne(acc.z) | (bf16rne(acc.w) << 16));
        float4 o = out[idx];
        o.x += acc.x; o.y += acc.y; o.z += acc.z; o.w += acc.w;
        out[idx] = o;
    } else {
        float4 o = out[idx];
        o.x = (o.x + acc.x) * 0.25f;
        o.y = (o.y + acc.y) * 0.25f;
        o.z = (o.z + acc.z) * 0.25f;
        o.w = (o.w + acc.w) * 0.25f;
        out[idx] = o;
    }
}

extern "C" void kernel_launch(void* const* d_in, const int* in_sizes, int n_in,
                              void* d_out, int out_size, void* d_ws, size_t ws_size,
                              hipStream_t stream) {
    const float* ue   = (const float*)d_in[0];
    const float* ie   = (const float*)d_in[1];
    const float* vals = (const float*)d_in[2];
    const int*   rows = (const int*)d_in[3];
    const int*   cols = (const int*)d_in[4];
    float* out = (float*)d_out;

    // workspace (~115.8 MB)
    uint2* xa     = (uint2*)d_ws;                // 19.2 MB (bf16 x, ping)
    uint2* xb     = xa + NVEC4;                  // 19.2 MB (bf16 x, pong)
    int2*  csr    = (int2*)(xb + NVEC4);         // 38.4 MB
    int2*  stage  = csr + NNZE;                  // 38.4 MB
    int*   rowptr = (int*)(stage + NNZE);        // 150001 ints
    int*   bucketCnt = rowptr + (NNODES + 1);    // 512
    int*   bbase  = bucketCnt + NB;              // 513
    int*   gcur   = bbase + (NB + 1);            // 512

    const int BLK = 256;
    const int spmmBlocks = NNODES * 16 / BLK;    // 9375

    lg_init<<<2048, BLK, 0, stream>>>((const float4*)ue, (const float4*)ie, xa, (float4*)out);
    hipMemsetAsync(bucketCnt, 0, NB * sizeof(int), stream);
    lg_bcnt<<<P1_BLOCKS, BLK, 0, stream>>>(rows, bucketCnt);
    lg_bscan<<<1, NB, 0, stream>>>(bucketCnt, bbase, gcur);
    lg_part1<<<P1_BLOCKS, BLK, 0, stream>>>(rows, cols, vals, gcur, stage);
    lg_part2<<<NB, 512, 0, stream>>>(bbase, stage, csr, rowptr);

    lg_spmm<0><<<spmmBlocks, BLK, 0, stream>>>(rowptr, csr, xa, xb, (float4*)out);
    lg_spmm<0><<<spmmBlocks, BLK, 0, stream>>>(rowptr, csr, xb, xa, (float4*)out);
    lg_spmm<1><<<spmmBlocks, BLK, 0, stream>>>(rowptr, csr, xa, nullptr, (float4*)out);
}